// Round 7
// baseline (178.445 us; speedup 1.0000x reference)
//
#include <hip/hip_runtime.h>
#include <hip/hip_bf16.h>

// AttentionBlock: x(2,512,64,64) fp32 -> GN(32 groups) -> QKV(1536x512) ->
// 8-head attention (L=4096, ch=64) -> proj(512x512) -> +x.
// All GEMM/attention math in FP16 MFMA (16x16x32_f16), fp32 accumulate.
// Attention: swapped QK^T (S^T = K·Q^T) -> per-lane scalar softmax (R2-exact
// numerics: true running max, P in (0,1], fp32 unquantized denominator);
// P->B-frag via v_cvt_pkrtz_f16_f32 + permlane swaps; in-block kv-split x2.

typedef _Float16 f16;
typedef __attribute__((ext_vector_type(8))) _Float16 f16x8;
typedef __attribute__((ext_vector_type(4))) float f32x4;

#define LL 4096
#define CC 512

__device__ __forceinline__ ushort f2h(float f) {
    f16 h = (f16)f;                       // v_cvt_f16_f32 (RNE)
    return *reinterpret_cast<ushort*>(&h);
}

// butterfly reduce across lanes +-16 / +-32 via gfx950 permlane swaps.
// After swap with a==b==x, {a,b} at each lane == {x[lane], x[lane^16]} as a
// set -> any commutative op combines the pair.
__device__ __forceinline__ float bfly_max16(float x) {
    int a = __float_as_int(x), b = a;
    asm("v_permlane16_swap_b32 %0, %1" : "+v"(a), "+v"(b));
    return fmaxf(__int_as_float(a), __int_as_float(b));
}
__device__ __forceinline__ float bfly_max32(float x) {
    int a = __float_as_int(x), b = a;
    asm("v_permlane32_swap_b32 %0, %1" : "+v"(a), "+v"(b));
    return fmaxf(__int_as_float(a), __int_as_float(b));
}
__device__ __forceinline__ float bfly_add16(float x) {
    int a = __float_as_int(x), b = a;
    asm("v_permlane16_swap_b32 %0, %1" : "+v"(a), "+v"(b));
    return __int_as_float(a) + __int_as_float(b);
}
__device__ __forceinline__ float bfly_add32(float x) {
    int a = __float_as_int(x), b = a;
    asm("v_permlane32_swap_b32 %0, %1" : "+v"(a), "+v"(b));
    return __int_as_float(a) + __int_as_float(b);
}
// pack two f32 -> two f16 in one instr (v_cvt_pkrtz_f16_f32)
__device__ __forceinline__ uint pkh(float lo, float hi) {
    union { decltype(__builtin_amdgcn_cvt_pkrtz(0.f, 0.f)) h; uint u; } r;
    r.h = __builtin_amdgcn_cvt_pkrtz(lo, hi);
    return r.u;
}

// ---------------- K0: fp32 weights -> fp16 ----------------
__global__ __launch_bounds__(256) void k_convert(
        const float* __restrict__ qkv_w, const float* __restrict__ proj_w,
        ushort* __restrict__ wq, ushort* __restrict__ wp) {
    const int NQ = 1536 * 512;
    int base = (blockIdx.x * 256 + threadIdx.x) * 4;
    const float* src; ushort* dst; int off;
    if (base < NQ) { src = qkv_w; dst = wq; off = base; }
    else           { src = proj_w; dst = wp; off = base - NQ; }
    float4 v = *reinterpret_cast<const float4*>(src + off);
    ushort4 o;
    o.x = f2h(v.x); o.y = f2h(v.y); o.z = f2h(v.z); o.w = f2h(v.w);
    *reinterpret_cast<ushort4*>(dst + off) = o;
}

// ---------------- K1a: GN partial sums ----------------
__global__ __launch_bounds__(256) void k_gn_part(
        const float* __restrict__ x, float2* __restrict__ part) {
    int bg = blockIdx.x, sl = blockIdx.y;
    const float4* xg = reinterpret_cast<const float4*>(x + (size_t)bg * 65536) + sl * 2048;
    float s = 0.f, ss = 0.f;
    for (int i = threadIdx.x; i < 2048; i += 256) {
        float4 v = xg[i];
        s  += v.x + v.y + v.z + v.w;
        ss += v.x*v.x + v.y*v.y + v.z*v.z + v.w*v.w;
    }
    #pragma unroll
    for (int m = 32; m; m >>= 1) { s += __shfl_xor(s, m); ss += __shfl_xor(ss, m); }
    __shared__ float red[8];
    int wid = threadIdx.x >> 6;
    if ((threadIdx.x & 63) == 0) { red[wid*2] = s; red[wid*2+1] = ss; }
    __syncthreads();
    if (threadIdx.x == 0) {
        s  = red[0] + red[2] + red[4] + red[6];
        ss = red[1] + red[3] + red[5] + red[7];
        part[bg * 8 + sl] = make_float2(s, ss);
    }
}

// ---------------- K1b: finalize stats ----------------
__global__ void k_gn_stats(const float2* __restrict__ part, float2* __restrict__ stats) {
    int i = threadIdx.x;  // 0..63
    float s = 0.f, ss = 0.f;
    #pragma unroll
    for (int j = 0; j < 8; ++j) { float2 p = part[i*8 + j]; s += p.x; ss += p.y; }
    float mean = s * (1.f/65536.f);
    float var  = ss * (1.f/65536.f) - mean*mean;
    stats[i] = make_float2(mean, rsqrtf(var + 1e-5f));
}

// ---------------- K1c: apply GN, write hid as (b, l, c) fp16 ----------------
__global__ __launch_bounds__(256) void k_gn_apply(
        const float* __restrict__ x, const float* __restrict__ gamma,
        const float* __restrict__ beta, const float2* __restrict__ stats,
        ushort* __restrict__ hid) {
    int bg = blockIdx.y;
    int b = bg >> 5, c0 = (bg & 31) * 16;
    int l0 = blockIdx.x * 256;
    float2 st = stats[bg];
    __shared__ __align__(16) ushort tile[16][256];
    int tid = threadIdx.x;
    const float* xg = x + (size_t)(b * CC + c0) * LL;
    #pragma unroll
    for (int sub = 0; sub < 4; ++sub) {
        int r = sub * 4 + (tid >> 6);
        int c4 = (tid & 63) * 4;
        float4 v = *reinterpret_cast<const float4*>(xg + (size_t)r * LL + l0 + c4);
        float ga = gamma[c0 + r] * st.y;
        float be = beta[c0 + r] - st.x * ga;
        tile[r][c4+0] = f2h(v.x * ga + be);
        tile[r][c4+1] = f2h(v.y * ga + be);
        tile[r][c4+2] = f2h(v.z * ga + be);
        tile[r][c4+3] = f2h(v.w * ga + be);
    }
    __syncthreads();
    union { ushort u[16]; uint4 q[2]; } pk;
    #pragma unroll
    for (int r = 0; r < 16; ++r) pk.u[r] = tile[r][tid];
    ushort* dst = hid + ((size_t)b * LL + l0 + tid) * CC + c0;
    *reinterpret_cast<uint4*>(dst)     = pk.q[0];
    *reinterpret_cast<uint4*>(dst + 8) = pk.q[1];
}

// ---------------- K2: QKV GEMM ----------------
// Q scale folds 0.125 (=ch^-0.5) AND log2(e) so attention exp is bare v_exp_f32.
#define QSCALE 0.18033688011112042f   // 0.125 * log2(e)
__global__ __launch_bounds__(256) void k_qkv(
        const ushort* __restrict__ wq, const ushort* __restrict__ hid,
        const float* __restrict__ qkv_b,
        ushort* __restrict__ q_ws, ushort* __restrict__ k_ws, ushort* __restrict__ v_ws) {
    int b = blockIdx.z;
    int n0 = blockIdx.x * 128;
    int m0 = blockIdx.y * 128;
    int tid = threadIdx.x;
    int w = tid >> 6, lane = tid & 63, h = lane >> 4, lm = lane & 15;
    int m0w = (w & 1) * 64, n0w = (w >> 1) * 64;
    __shared__ __align__(16) ushort As[128][40];
    __shared__ __align__(16) ushort Bs[128][40];
    f32x4 acc[4][4] = {};
    const ushort* Ag = wq + (size_t)m0 * CC;
    const ushort* Bg = hid + (size_t)(b * LL + n0) * CC;
    for (int k0 = 0; k0 < CC; k0 += 32) {
        __syncthreads();
        #pragma unroll
        for (int i = 0; i < 2; ++i) {
            int flat = tid + i * 256;
            int row = flat >> 2, ch = (flat & 3) * 8;
            *reinterpret_cast<uint4*>(&As[row][ch]) =
                *reinterpret_cast<const uint4*>(Ag + (size_t)row * CC + k0 + ch);
            *reinterpret_cast<uint4*>(&Bs[row][ch]) =
                *reinterpret_cast<const uint4*>(Bg + (size_t)row * CC + k0 + ch);
        }
        __syncthreads();
        f16x8 af[4], bfr[4];
        #pragma unroll
        for (int mi = 0; mi < 4; ++mi)
            af[mi] = *reinterpret_cast<const f16x8*>(&As[m0w + mi*16 + lm][h*8]);
        #pragma unroll
        for (int nj = 0; nj < 4; ++nj)
            bfr[nj] = *reinterpret_cast<const f16x8*>(&Bs[n0w + nj*16 + lm][h*8]);
        #pragma unroll
        for (int mi = 0; mi < 4; ++mi)
            #pragma unroll
            for (int nj = 0; nj < 4; ++nj)
                acc[mi][nj] = __builtin_amdgcn_mfma_f32_16x16x32_f16(af[mi], bfr[nj], acc[mi][nj], 0, 0, 0);
    }
    #pragma unroll
    for (int mi = 0; mi < 4; ++mi) {
        int o_base = m0 + m0w + mi * 16 + h * 4;
        float4 bias = *reinterpret_cast<const float4*>(qkv_b + o_base);
        int head = o_base / 192;
        int rem  = o_base - head * 192;
        int part = rem >> 6;
        int ch   = rem & 63;
        #pragma unroll
        for (int nj = 0; nj < 4; ++nj) {
            int l = n0 + n0w + nj * 16 + lm;
            float v0 = acc[mi][nj][0] + bias.x;
            float v1 = acc[mi][nj][1] + bias.y;
            float v2 = acc[mi][nj][2] + bias.z;
            float v3 = acc[mi][nj][3] + bias.w;
            if (part == 0) {
                ushort4 pk;
                pk.x = f2h(v0 * QSCALE); pk.y = f2h(v1 * QSCALE);
                pk.z = f2h(v2 * QSCALE); pk.w = f2h(v3 * QSCALE);
                *reinterpret_cast<ushort4*>(q_ws + ((size_t)(b*8 + head) * LL + l) * 64 + ch) = pk;
            } else if (part == 1) {
                ushort4 pk;
                pk.x = f2h(v0); pk.y = f2h(v1); pk.z = f2h(v2); pk.w = f2h(v3);
                *reinterpret_cast<ushort4*>(k_ws + ((size_t)(b*8 + head) * LL + l) * 64 + ch) = pk;
            } else {
                ushort* vp = v_ws + ((size_t)(b*8 + head) * 64 + ch) * LL + l;
                vp[0] = f2h(v0); vp[LL] = f2h(v1); vp[2*LL] = f2h(v2); vp[3*LL] = f2h(v3);
            }
        }
    }
}

// ---------------- K3: flash attention v6 (fp16, R2-exact softmax, kv-split x2) ----------------
// grid (32 q-blocks, 16 bh); 8 waves/block; group g = w>>2 handles kv half
// [g*2048, +2048) for the block's 128 queries; wave w4 = w&3 owns 32 q.
// True running max (rescale only when max grows; P in (0,1]); denominator =
// fp32 sum of unquantized P via in-lane adds + permlane butterflies.
// Group 1 spills partials to LDS; group 0 merges, normalizes, writes fp16.
__global__ __launch_bounds__(512, 4) void k_attn(
        const ushort* __restrict__ q_ws, const ushort* __restrict__ k_ws,
        const ushort* __restrict__ v_ws, ushort* __restrict__ o_ws) {
    int bh = blockIdx.y;
    int tid = threadIdx.x;
    int w = tid >> 6, lane = tid & 63, h = lane >> 4, lm = lane & 15;
    int g = w >> 2, w4 = w & 3;
    int t0 = blockIdx.x * 128 + w4 * 32;

    __shared__ __align__(16) char smem[2 * 36864];
    // [g][buf][row][col]
    ushort (*Ks)[2][64][72]  = reinterpret_cast<ushort(*)[2][64][72]>(smem);
    ushort (*Vts)[2][64][72] = reinterpret_cast<ushort(*)[2][64][72]>(smem + 36864);
    float* msc = reinterpret_cast<float*>(smem);   // epilogue merge scratch (aliases Ks)

    // Q fragments (B-operand): q = t0+qt*16+lm, c = kc*32+h*8
    f16x8 bQ[2][2];
    {
        const ushort* qp = q_ws + ((size_t)bh * LL + t0 + lm) * 64 + h * 8;
        bQ[0][0] = *reinterpret_cast<const f16x8*>(qp);
        bQ[0][1] = *reinterpret_cast<const f16x8*>(qp + 32);
        bQ[1][0] = *reinterpret_cast<const f16x8*>(qp + 16 * 64);
        bQ[1][1] = *reinterpret_cast<const f16x8*>(qp + 16 * 64 + 32);
    }

    int srow = lane >> 3, scol = (lane & 7) * 8;   // staging: 16 rows per wave-of-group
    const ushort* kgp = k_ws + ((size_t)bh * LL + g * 2048 + w4 * 16 + srow) * 64 + scol;
    const ushort* vgp = v_ws + ((size_t)bh * 64 + w4 * 16 + srow) * LL + g * 2048 + scol;
    uint4 kr0, kr1, vr0, vr1;
    auto issue = [&]() {
        kr0 = *reinterpret_cast<const uint4*>(kgp);
        kr1 = *reinterpret_cast<const uint4*>(kgp + 8 * 64);
        vr0 = *reinterpret_cast<const uint4*>(vgp);
        vr1 = *reinterpret_cast<const uint4*>(vgp + 8 * LL);
        kgp += 64 * 64;   // next 64 kv rows
        vgp += 64;        // next 64 kv cols
    };
    issue();

    float mr[2] = {-1e30f, -1e30f};
    float lr[2] = {0.f, 0.f};        // fp32 softmax denominator (unquantized P)
    f32x4 accO[2][4] = {};           // [qt][nj] numerator tiles

    for (int t = 0; t < 32; ++t) {
        int p = t & 1;
        {   // commit staged tile into this group's buf p
            int row = w4 * 16 + srow;
            *reinterpret_cast<uint4*>(&Ks [g][p][row    ][scol]) = kr0;
            *reinterpret_cast<uint4*>(&Ks [g][p][row + 8][scol]) = kr1;
            *reinterpret_cast<uint4*>(&Vts[g][p][row    ][scol]) = vr0;
            *reinterpret_cast<uint4*>(&Vts[g][p][row + 8][scol]) = vr1;
        }
        if (t < 31) issue();   // stays in flight across the whole compute phase
        __syncthreads();

        // ---- S^T[kv][q] = mfma(K, Q): lane: q=lm, kv = ss*16 + h*4 + r ----
        f32x4 sf[2][4] = {};
        __builtin_amdgcn_s_setprio(1);
        #pragma unroll
        for (int ss = 0; ss < 4; ++ss)
            #pragma unroll
            for (int kc = 0; kc < 2; ++kc) {
                f16x8 aK = *reinterpret_cast<const f16x8*>(&Ks[g][p][ss*16 + lm][kc*32 + h*8]);
                sf[0][ss] = __builtin_amdgcn_mfma_f32_16x16x32_f16(aK, bQ[0][kc], sf[0][ss], 0, 0, 0);
                sf[1][ss] = __builtin_amdgcn_mfma_f32_16x16x32_f16(aK, bQ[1][kc], sf[1][ss], 0, 0, 0);
            }
        __builtin_amdgcn_s_setprio(0);

        #pragma unroll
        for (int qt = 0; qt < 2; ++qt) {
            // ---- tile max over kv (in-lane 16 values + cross-h butterflies) ----
            float a0 = fmaxf(fmaxf(sf[qt][0][0], sf[qt][0][1]), fmaxf(sf[qt][0][2], sf[qt][0][3]));
            float a1 = fmaxf(fmaxf(sf[qt][1][0], sf[qt][1][1]), fmaxf(sf[qt][1][2], sf[qt][1][3]));
            float a2 = fmaxf(fmaxf(sf[qt][2][0], sf[qt][2][1]), fmaxf(sf[qt][2][2], sf[qt][2][3]));
            float a3 = fmaxf(fmaxf(sf[qt][3][0], sf[qt][3][1]), fmaxf(sf[qt][3][2], sf[qt][3][3]));
            float tm = fmaxf(fmaxf(a0, a1), fmaxf(a2, a3));
            tm = bfly_max16(tm);
            tm = bfly_max32(tm);
            // ---- true running max: rescale whenever max grows (exact) ----
            if (!__all(tm <= mr[qt])) {
                float mn = fmaxf(mr[qt], tm);
                float corr = __builtin_amdgcn_exp2f(mr[qt] - mn);
                mr[qt] = mn;
                lr[qt] *= corr;
                #pragma unroll
                for (int nj = 0; nj < 4; ++nj)
                    #pragma unroll
                    for (int r = 0; r < 4; ++r)
                        accO[qt][nj][r] *= corr;
            }
            // ---- P = 2^(S'-m) in (0,1] (log2e pre-folded into Q) ----
            #pragma unroll
            for (int ss = 0; ss < 4; ++ss)
                #pragma unroll
                for (int r = 0; r < 4; ++r)
                    sf[qt][ss][r] = __builtin_amdgcn_exp2f(sf[qt][ss][r] - mr[qt]);

            // ---- denominator: fp32 sum of UNQUANTIZED P ----
            float rs = (((sf[qt][0][0] + sf[qt][0][1]) + (sf[qt][0][2] + sf[qt][0][3]))
                      + ((sf[qt][1][0] + sf[qt][1][1]) + (sf[qt][1][2] + sf[qt][1][3])))
                     + (((sf[qt][2][0] + sf[qt][2][1]) + (sf[qt][2][2] + sf[qt][2][3]))
                      + ((sf[qt][3][0] + sf[qt][3][1]) + (sf[qt][3][2] + sf[qt][3][3])));
            rs = bfly_add16(rs);
            rs = bfly_add32(rs);
            lr[qt] += rs;

            // ---- P -> B-frag: pack pairs, permlane redistribute ----
            f16x8 bP[2];
            #pragma unroll
            for (int kc = 0; kc < 2; ++kc) {
                uint a = pkh(sf[qt][2*kc  ][0], sf[qt][2*kc  ][1]);
                uint b = pkh(sf[qt][2*kc  ][2], sf[qt][2*kc  ][3]);
                uint c = pkh(sf[qt][2*kc+1][0], sf[qt][2*kc+1][1]);
                uint d = pkh(sf[qt][2*kc+1][2], sf[qt][2*kc+1][3]);
                asm("v_permlane32_swap_b32 %0, %1" : "+v"(a), "+v"(c));
                asm("v_permlane32_swap_b32 %0, %1" : "+v"(b), "+v"(d));
                asm("v_permlane16_swap_b32 %0, %1" : "+v"(a), "+v"(c));
                asm("v_permlane16_swap_b32 %0, %1" : "+v"(b), "+v"(d));
                union { uint u[4]; f16x8 v; } pw;
                pw.u[0] = a; pw.u[1] = b; pw.u[2] = c; pw.u[3] = d;
                bP[kc] = pw.v;
            }

            // ---- PV: O^T[d][q] += V^T-frag * P-frag ----
            __builtin_amdgcn_s_setprio(1);
            #pragma unroll
            for (int kc = 0; kc < 2; ++kc)
                #pragma unroll
                for (int nj = 0; nj < 4; ++nj) {
                    f16x8 aV = *reinterpret_cast<const f16x8*>(&Vts[g][p][nj*16 + lm][kc*32 + h*8]);
                    accO[qt][nj] = __builtin_amdgcn_mfma_f32_16x16x32_f16(aV, bP[kc], accO[qt][nj], 0, 0, 0);
                }
            __builtin_amdgcn_s_setprio(0);
        }
    }

    // ---- merge the two kv-halves in LDS (aliases the dead K/V buffers) ----
    // 36 f32/thread: 32 accO + 2 lr + 2 mr; 512 threads/group -> 36864 B (=Ks)
    __syncthreads();
    if (g == 1) {
        float* dst = msc + (size_t)(w4 * 64 + lane) * 36;
        #pragma unroll
        for (int qt = 0; qt < 2; ++qt)
            #pragma unroll
            for (int nj = 0; nj < 4; ++nj)
                #pragma unroll
                for (int r = 0; r < 4; ++r)
                    dst[(qt * 4 + nj) * 4 + r] = accO[qt][nj][r];
        dst[32] = lr[0]; dst[33] = lr[1];
        dst[34] = mr[0]; dst[35] = mr[1];
    }
    __syncthreads();
    if (g == 0) {
        const float* src = msc + (size_t)(w4 * 64 + lane) * 36;
        #pragma unroll
        for (int qt = 0; qt < 2; ++qt) {
            float m1 = src[34 + qt];
            float M  = fmaxf(mr[qt], m1);
            float c0 = __builtin_amdgcn_exp2f(mr[qt] - M);
            float c1 = __builtin_amdgcn_exp2f(m1 - M);
            float l  = lr[qt] * c0 + src[32 + qt] * c1;
            float iv = 1.f / l;            // per-lane: lr is replicated across h
            #pragma unroll
            for (int nj = 0; nj < 4; ++nj) {
                ushort4 o4;
                o4.x = f2h((accO[qt][nj][0] * c0 + src[(qt*4+nj)*4 + 0] * c1) * iv);
                o4.y = f2h((accO[qt][nj][1] * c0 + src[(qt*4+nj)*4 + 1] * c1) * iv);
                o4.z = f2h((accO[qt][nj][2] * c0 + src[(qt*4+nj)*4 + 2] * c1) * iv);
                o4.w = f2h((accO[qt][nj][3] * c0 + src[(qt*4+nj)*4 + 3] * c1) * iv);
                *reinterpret_cast<ushort4*>(
                    o_ws + ((size_t)bh * LL + t0 + qt*16 + lm) * 64 + nj*16 + h*4) = o4;
            }
        }
    }
}

// ---------------- K4: proj GEMM + bias + residual ----------------
__global__ __launch_bounds__(256) void k_proj(
        const ushort* __restrict__ wp, const ushort* __restrict__ o_ws,
        const float* __restrict__ proj_b, const float* __restrict__ x,
        float* __restrict__ out) {
    int b = blockIdx.z;
    int n0 = blockIdx.x * 128;
    int m0 = blockIdx.y * 128;
    int tid = threadIdx.x;
    int w = tid >> 6, lane = tid & 63, h = lane >> 4, lm = lane & 15;
    int m0w = (w & 1) * 64, n0w = (w >> 1) * 64;
    __shared__ __align__(16) ushort As[128][40];
    __shared__ __align__(16) ushort Bs[128][40];
    f32x4 acc[4][4] = {};
    const ushort* Ag = wp + (size_t)m0 * CC;
    for (int k0 = 0; k0 < CC; k0 += 32) {
        const ushort* Bg = o_ws + ((size_t)(b * 8 + (k0 >> 6)) * LL + n0) * 64 + (k0 & 63);
        __syncthreads();
        #pragma unroll
        for (int i = 0; i < 2; ++i) {
            int flat = tid + i * 256;
            int row = flat >> 2, ch = (flat & 3) * 8;
            *reinterpret_cast<uint4*>(&As[row][ch]) =
                *reinterpret_cast<const uint4*>(Ag + (size_t)row * CC + k0 + ch);
            *reinterpret_cast<uint4*>(&Bs[row][ch]) =
                *reinterpret_cast<const uint4*>(Bg + (size_t)row * 64 + ch);
        }
        __syncthreads();
        f16x8 af[4], bfr[4];
        #pragma unroll
        for (int mi = 0; mi < 4; ++mi)
            af[mi] = *reinterpret_cast<const f16x8*>(&As[m0w + mi*16 + lm][h*8]);
        #pragma unroll
        for (int nj = 0; nj < 4; ++nj)
            bfr[nj] = *reinterpret_cast<const f16x8*>(&Bs[n0w + nj*16 + lm][h*8]);
        #pragma unroll
        for (int mi = 0; mi < 4; ++mi)
            #pragma unroll
            for (int nj = 0; nj < 4; ++nj)
                acc[mi][nj] = __builtin_amdgcn_mfma_f32_16x16x32_f16(af[mi], bfr[nj], acc[mi][nj], 0, 0, 0);
    }
    #pragma unroll
    for (int mi = 0; mi < 4; ++mi) {
        int o = m0 + m0w + mi * 16 + h * 4;
        float4 bias = *reinterpret_cast<const float4*>(proj_b + o);
        #pragma unroll
        for (int nj = 0; nj < 4; ++nj) {
            int l = n0 + n0w + nj * 16 + lm;
            size_t xo = (size_t)(b * CC + o) * LL + l;
            out[xo]          = acc[mi][nj][0] + bias.x + x[xo];
            out[xo +   LL]   = acc[mi][nj][1] + bias.y + x[xo +   LL];
            out[xo + 2*LL]   = acc[mi][nj][2] + bias.z + x[xo + 2*LL];
            out[xo + 3*LL]   = acc[mi][nj][3] + bias.w + x[xo + 3*LL];
        }
    }
}

extern "C" void kernel_launch(void* const* d_in, const int* in_sizes, int n_in,
                              void* d_out, int out_size, void* d_ws, size_t ws_size,
                              hipStream_t stream) {
    const float* x      = (const float*)d_in[0];
    const float* norm_w = (const float*)d_in[1];
    const float* norm_b = (const float*)d_in[2];
    const float* qkv_w  = (const float*)d_in[3];
    const float* qkv_b  = (const float*)d_in[4];
    const float* proj_w = (const float*)d_in[5];
    const float* proj_b = (const float*)d_in[6];
    float* out = (float*)d_out;
    char* ws = (char*)d_ws;

    ushort* wq    = (ushort*)(ws);                         // 1536*512 f16
    ushort* wp    = (ushort*)(ws + 1572864);               // 512*512 f16
    ushort* hid   = (ushort*)(ws + 2097152);               // (2,4096,512) f16
    ushort* q_ws  = (ushort*)(ws + 10485760);              // (16,4096,64) f16
    ushort* k_ws  = (ushort*)(ws + 18874368);              // (16,4096,64) f16
    ushort* v_ws  = (ushort*)(ws + 27262976);              // (16,64,4096) f16
    ushort* o_ws  = (ushort*)(ws + 35651584);              // (16,4096,64) f16
    float2* part  = (float2*)(ws + 44040192);              // 64*8 float2
    float2* stats = (float2*)(ws + 44044288);              // 64 float2

    k_convert<<<dim3(1024), dim3(256), 0, stream>>>(qkv_w, proj_w, wq, wp);
    k_gn_part<<<dim3(64, 8), dim3(256), 0, stream>>>(x, part);
    k_gn_stats<<<dim3(1), dim3(64), 0, stream>>>(part, stats);
    k_gn_apply<<<dim3(16, 64), dim3(256), 0, stream>>>(x, norm_w, norm_b, stats, hid);
    k_qkv<<<dim3(32, 12, 2), dim3(256), 0, stream>>>(wq, hid, qkv_b, q_ws, k_ws, v_ws);
    k_attn<<<dim3(32, 16), dim3(512), 0, stream>>>(q_ws, k_ws, v_ws, o_ws);
    k_proj<<<dim3(32, 4, 2), dim3(256), 0, stream>>>(wp, o_ws, proj_b, x, out);
}